// Round 9
// baseline (116.611 us; speedup 1.0000x reference)
//
#include <hip/hip_runtime.h>
#include <hip/hip_fp16.h>

#define D_FEAT 128
#define CAP 32          // per-node bin capacity; overflow handled exactly via list
#define CSTRIDE 16      // count[] spread: one counter per 64B line (atomic-queue probe)

// ---------------- fast path ----------------

// Streams h once: writes fp16 mirror (for the random-gather phase) AND the
// exact f32 h-copy into out[:, 0:128] (removing that work from gather).
__global__ void __launch_bounds__(256) cast_copy_kernel(
    const float* __restrict__ h, __half* __restrict__ hb,
    float* __restrict__ out, int n_elems)
{
    const int t      = blockIdx.x * blockDim.x + threadIdx.x;
    const int stride = gridDim.x * blockDim.x;
    const int n4     = n_elems >> 2;   // n_elems = N*128, divisible by 4
    for (int i = t; i < n4; i += stride) {
        const float4 v = ((const float4*)h)[i];
        ((__half2*)hb)[2 * i]     = __float22half2_rn(make_float2(v.x, v.y));
        ((__half2*)hb)[2 * i + 1] = __float22half2_rn(make_float2(v.z, v.w));
        const int n = i >> 5;          // node
        const int q = i & 31;          // feature quad
        ((float4*)(out + (size_t)n * 2 * D_FEAT))[q] = v;   // cols 0..127
    }
}

// Scalar 1-edge/thread; count spread to 1 counter / 64B line.
__global__ void __launch_bounds__(256) fill_bins_kernel(
    const float* __restrict__ w, const int* __restrict__ src,
    const int* __restrict__ dst,
    int* __restrict__ count, int* __restrict__ ovf_count,
    int* __restrict__ ovf_list, int2* __restrict__ bins, int n_edges)
{
    int i = blockIdx.x * blockDim.x + threadIdx.x;
    const int stride = gridDim.x * blockDim.x;
    for (int e = i; e < n_edges; e += stride) {
        const int d = dst[e];
        const int pos = atomicAdd(&count[(size_t)d * CSTRIDE], 1);
        if (pos < CAP) {
            bins[(size_t)d * CAP + pos] = make_int2(src[e], __float_as_int(w[e]));
        } else {
            const int o = atomicAdd(ovf_count, 1);
            ovf_list[o] = e;
        }
    }
}

// One wave per node, MLP-8, fp16 rows (256B per row). Writes only the h_N half.
__global__ void __launch_bounds__(256) gather_kernel(
    const __half* __restrict__ hb, const int* __restrict__ count,
    const int2* __restrict__ bins, float* __restrict__ out, int n_nodes)
{
    const int lane = threadIdx.x & 63;
    const int wave = (blockIdx.x * blockDim.x + threadIdx.x) >> 6;
    if (wave >= n_nodes) return;
    const int n   = wave;
    const int cnt = count[(size_t)n * CSTRIDE];
    const int c   = cnt < CAP ? cnt : CAP;
    float2 acc = make_float2(0.0f, 0.0f);
    const int2* bp  = bins + (size_t)n * CAP;
    const int4* bp4 = (const int4*)bp;

#define HROW(s) __half22float2(((const __half2*)(hb + (size_t)(s) * D_FEAT))[lane])

    int k = 0;
    for (; k + 8 <= c; k += 8) {
        const int kk = k >> 1;
        const int4 p0 = bp4[kk + 0];
        const int4 p1 = bp4[kk + 1];
        const int4 p2 = bp4[kk + 2];
        const int4 p3 = bp4[kk + 3];
        const float2 h0 = HROW(p0.x);
        const float2 h1 = HROW(p0.z);
        const float2 h2 = HROW(p1.x);
        const float2 h3 = HROW(p1.z);
        const float2 h4 = HROW(p2.x);
        const float2 h5 = HROW(p2.z);
        const float2 h6 = HROW(p3.x);
        const float2 h7 = HROW(p3.z);
        const float w0 = __int_as_float(p0.y), w1 = __int_as_float(p0.w);
        const float w2 = __int_as_float(p1.y), w3 = __int_as_float(p1.w);
        const float w4 = __int_as_float(p2.y), w5 = __int_as_float(p2.w);
        const float w6 = __int_as_float(p3.y), w7 = __int_as_float(p3.w);
        acc.x = fmaf(h0.x, w0, acc.x); acc.y = fmaf(h0.y, w0, acc.y);
        acc.x = fmaf(h1.x, w1, acc.x); acc.y = fmaf(h1.y, w1, acc.y);
        acc.x = fmaf(h2.x, w2, acc.x); acc.y = fmaf(h2.y, w2, acc.y);
        acc.x = fmaf(h3.x, w3, acc.x); acc.y = fmaf(h3.y, w3, acc.y);
        acc.x = fmaf(h4.x, w4, acc.x); acc.y = fmaf(h4.y, w4, acc.y);
        acc.x = fmaf(h5.x, w5, acc.x); acc.y = fmaf(h5.y, w5, acc.y);
        acc.x = fmaf(h6.x, w6, acc.x); acc.y = fmaf(h6.y, w6, acc.y);
        acc.x = fmaf(h7.x, w7, acc.x); acc.y = fmaf(h7.y, w7, acc.y);
    }
    for (; k < c; ++k) {
        const int2  b  = bp[k];
        const float ww = __int_as_float(b.y);
        const float2 hv = HROW(b.x);
        acc.x = fmaf(hv.x, ww, acc.x);
        acc.y = fmaf(hv.y, ww, acc.y);
    }
#undef HROW

    const float inv = 1.0f / fmaxf((float)cnt, 1.0f);
    float2* orow = (float2*)(out + (size_t)n * 2 * D_FEAT + D_FEAT);
    orow[lane] = make_float2(acc.x * inv, acc.y * inv);       // cols 128..255
}

// Exact fixup for edges that exceeded CAP (expected: ~few). Runs AFTER gather.
__global__ void __launch_bounds__(256) overflow_kernel(
    const __half* __restrict__ hb, const float* __restrict__ w,
    const int* __restrict__ src, const int* __restrict__ dst,
    const int* __restrict__ count, const int* __restrict__ ovf_count,
    const int* __restrict__ ovf_list, float* __restrict__ out)
{
    const int novf = *ovf_count;
    if (novf == 0) return;
    const int lane  = threadIdx.x & 63;
    const int wave  = (blockIdx.x * blockDim.x + threadIdx.x) >> 6;
    const int nwave = (gridDim.x * blockDim.x) >> 6;
    for (int idx = wave; idx < novf; idx += nwave) {
        const int e = ovf_list[idx];
        const int s = src[e];
        const int d = dst[e];
        const float scale = w[e] / fmaxf((float)count[(size_t)d * CSTRIDE], 1.0f);
        const float2 hv = __half22float2(((const __half2*)(hb + (size_t)s * D_FEAT))[lane]);
        float* od = out + (size_t)d * 2 * D_FEAT + D_FEAT + (lane << 1);
        atomicAdd(od,     hv.x * scale);
        atomicAdd(od + 1, hv.y * scale);
    }
}

// ---------------- fallback path (atomic version, exact f32) ----------------

__global__ void __launch_bounds__(256) edge_scatter_kernel(
    const float* __restrict__ h, const float* __restrict__ w,
    const int* __restrict__ src, const int* __restrict__ dst,
    float* __restrict__ out, float* __restrict__ deg, int n_edges)
{
    const int lane  = threadIdx.x & 63;
    const int wave  = (blockIdx.x * blockDim.x + threadIdx.x) >> 6;
    const int nwave = (gridDim.x * blockDim.x) >> 6;
    for (int e = wave; e < n_edges; e += nwave) {
        const int   s  = src[e];
        const int   d  = dst[e];
        const float we = w[e];
        const float2 hv = ((const float2*)(h + (size_t)s * D_FEAT))[lane];
        float* od = out + (size_t)d * (2 * D_FEAT) + D_FEAT + (lane << 1);
        atomicAdd(od,     hv.x * we);
        atomicAdd(od + 1, hv.y * we);
        if (lane == 0) atomicAdd(deg + d, 1.0f);
    }
}

__global__ void __launch_bounds__(256) finalize_kernel(
    const float* __restrict__ h, const float* __restrict__ deg,
    float* __restrict__ out, int n_nodes)
{
    int i = blockIdx.x * blockDim.x + threadIdx.x;
    const int total  = n_nodes * 32;
    const int stride = gridDim.x * blockDim.x;
    for (; i < total; i += stride) {
        const int n = i >> 5;
        const int q = i & 31;
        const float4 hv = ((const float4*)(h + (size_t)n * D_FEAT))[q];
        ((float4*)(out + (size_t)n * 2 * D_FEAT))[q] = hv;
        const float inv = 1.0f / fmaxf(deg[n], 1.0f);
        float4* ap = ((float4*)(out + (size_t)n * 2 * D_FEAT + D_FEAT)) + q;
        float4 a = *ap;
        a.x *= inv; a.y *= inv; a.z *= inv; a.w *= inv;
        *ap = a;
    }
}

// ---------------- launch ----------------

extern "C" void kernel_launch(void* const* d_in, const int* in_sizes, int n_in,
                              void* d_out, int out_size, void* d_ws, size_t ws_size,
                              hipStream_t stream) {
    const float* h   = (const float*)d_in[0];
    const float* w   = (const float*)d_in[1];
    const int*   src = (const int*)d_in[2];
    const int*   dst = (const int*)d_in[3];
    float* out = (float*)d_out;

    const int n_edges = in_sizes[1];
    const int n_nodes = in_sizes[0] / D_FEAT;
    const int n_hel   = in_sizes[0];         // N * 128

    // ws layout: count[n_nodes*CSTRIDE]+ovf(+pad) | bins[n_nodes*CAP] int2 | ovf_list[n_edges] | hb[n_hel] half
    const size_t count_bytes = ((size_t)n_nodes * CSTRIDE + 16) * sizeof(int);
    const size_t bins_bytes  = (size_t)n_nodes * CAP * sizeof(int2);
    const size_t ovf_bytes   = (size_t)n_edges * sizeof(int);
    const size_t hb_bytes    = (size_t)n_hel * sizeof(__half);
    const size_t need        = count_bytes + bins_bytes + ovf_bytes + hb_bytes;

    if (ws_size >= need && n_nodes <= 65536) {
        int*    count     = (int*)d_ws;
        int*    ovf_count = count + (size_t)n_nodes * CSTRIDE;
        int2*   bins      = (int2*)((char*)d_ws + count_bytes);
        int*    ovf_list  = (int*)((char*)d_ws + count_bytes + bins_bytes);
        __half* hb        = (__half*)((char*)d_ws + count_bytes + bins_bytes + ovf_bytes);

        (void)hipMemsetAsync(count, 0, count_bytes, stream);
        cast_copy_kernel<<<2048, 256, 0, stream>>>(h, hb, out, n_hel);
        fill_bins_kernel<<<2048, 256, 0, stream>>>(w, src, dst, count, ovf_count,
                                                   ovf_list, bins, n_edges);
        gather_kernel<<<(n_nodes + 3) / 4, 256, 0, stream>>>(hb, count, bins, out, n_nodes);
        overflow_kernel<<<64, 256, 0, stream>>>(hb, w, src, dst, count, ovf_count,
                                                ovf_list, out);
    } else {
        // Safety fallback: atomic scatter (correct, slower).
        float* deg = (float*)d_ws;
        (void)hipMemsetAsync(out, 0, (size_t)out_size * sizeof(float), stream);
        (void)hipMemsetAsync(deg, 0, (size_t)n_nodes * sizeof(float), stream);
        edge_scatter_kernel<<<2048, 256, 0, stream>>>(h, w, src, dst, out, deg, n_edges);
        finalize_kernel<<<2048, 256, 0, stream>>>(h, deg, out, n_nodes);
    }
}